// Round 17
// baseline (157.580 us; speedup 1.0000x reference)
//
#include <hip/hip_runtime.h>
#include <stdint.h>

typedef unsigned short ushort_t;
typedef unsigned int uint32;
typedef __attribute__((ext_vector_type(8))) short short8;
typedef __attribute__((ext_vector_type(4))) float f32x4;
typedef __attribute__((ext_vector_type(16))) float f32x16;
typedef __attribute__((ext_vector_type(4))) uint32 uint4v;

#define NSEQ 2048
#define BSZ 8
#define EMB 512
#define NHEAD 8
#define HDIM 64
#define MTOK (NSEQ*BSZ)      // 16384
#define NH_TOT (BSZ*NHEAD)   // 64
#define NP (NSEQ/128)        // 16 KV tile-pairs

#define VMCNT0 asm volatile("s_waitcnt vmcnt(0)" ::: "memory")
#define BAR __builtin_amdgcn_s_barrier()

__device__ __forceinline__ ushort_t f2bf(float f) {
  uint32_t u = __builtin_bit_cast(uint32_t, f);
  u += 0x7FFFu + ((u >> 16) & 1u);
  return (ushort_t)(u >> 16);
}
__device__ __forceinline__ float bf2f(ushort_t u) {
  uint32_t x = ((uint32_t)u) << 16;
  return __builtin_bit_cast(float, x);
}

__device__ __forceinline__ void gll16(const void* g, void* l) {
  __builtin_amdgcn_global_load_lds(
      (const __attribute__((address_space(1))) void*)g,
      (__attribute__((address_space(3))) void*)l, 16, 0, 0);
}

// swizzle slot for row r (8 slots of 16B within a 128B row)
__device__ __forceinline__ int SW(int r) { return (r & 7) ^ ((r >> 3) & 7); }

// ---------------- f32 -> bf16 convert (fused x3, grid-stride, 32B/iter) ----------------
__global__ void cvt3(const float* __restrict__ a, ushort_t* __restrict__ oa, int na8,
                     const float* __restrict__ b, ushort_t* __restrict__ ob, int nb8,
                     const float* __restrict__ c, ushort_t* __restrict__ oc, int nc8) {
  const int total = na8 + nb8 + nc8;
  const int stride = gridDim.x * blockDim.x;
  for (int i = blockIdx.x * blockDim.x + threadIdx.x; i < total; i += stride) {
    const float* src; ushort_t* dst; int j = i;
    if (j < na8) { src = a; dst = oa; }
    else {
      j -= na8;
      if (j < nb8) { src = b; dst = ob; }
      else { j -= nb8; src = c; dst = oc; }
    }
    float4 v0 = reinterpret_cast<const float4*>(src)[j*2];
    float4 v1 = reinterpret_cast<const float4*>(src)[j*2+1];
    union { ushort_t u[8]; uint4 q; } o;
    o.u[0] = f2bf(v0.x); o.u[1] = f2bf(v0.y); o.u[2] = f2bf(v0.z); o.u[3] = f2bf(v0.w);
    o.u[4] = f2bf(v1.x); o.u[5] = f2bf(v1.y); o.u[6] = f2bf(v1.z); o.u[7] = f2bf(v1.w);
    reinterpret_cast<uint4*>(dst)[j] = o.q;
  }
}

// ---------------- GEMM: C[M,N] = A[M,K] * B[N,K]^T + bias ----------------
// 128x128 tile, XCD-chunked swizzle, single-barrier counted pipeline.
// MODE 0: Q/K scalar scatter to [w3][head][n][hd]; V blocks (tn>=1024) -> VT[head][hd][n].
// MODE 1: f32 output.
template<int MODE>
__global__ __launch_bounds__(256, 2) void gemm_bt(
    const ushort_t* __restrict__ A, const ushort_t* __restrict__ B,
    const float* __restrict__ bias,
    float* __restrict__ Cf, ushort_t* __restrict__ Cq, ushort_t* __restrict__ VTq,
    int M, int N, int K)
{
  __shared__ __align__(16) ushort_t As[2][128*64];
  __shared__ __align__(16) ushort_t Bs[2][128*64];
  const int t = threadIdx.x;
  const int w = t >> 6, l = t & 63;

  const int nbx = gridDim.x;
  const int bid = blockIdx.x + nbx * blockIdx.y;
  const int per = (nbx * gridDim.y) >> 3;
  const int swz = (bid & 7) * per + (bid >> 3);
  const int tm = (swz / nbx) * 128, tn = (swz % nbx) * 128;
  const int wm = w >> 1, wn = w & 1;

  f32x4 acc[4][4] = {};

  auto STAGE = [&](int buf, int k0) {
    #pragma unroll
    for (int j = 0; j < 4; ++j) {
      int row = j*32 + w*8 + (l >> 3);
      int cole = ((l & 7) * 8) ^ ((row & 7) << 3);
      gll16(A + (size_t)(tm + row) * K + k0 + cole, &As[buf][0] + j*2048 + w*512 + l*8);
      gll16(B + (size_t)(tn + row) * K + k0 + cole, &Bs[buf][0] + j*2048 + w*512 + l*8);
    }
  };

  const int NK = K >> 6;                 // 8 for K=512
  STAGE(0, 0);

  int cur = 0;
  #pragma unroll 1
  for (int k = 0; k < NK; ++k) {
    VMCNT0;                              // own stage loads for tile k landed
    BAR;                                 // all waves staged k AND done reading buf[cur^1]
    if (k + 1 < NK) STAGE(cur ^ 1, (k + 1) << 6);

    const char* AsC = reinterpret_cast<const char*>(&As[cur][0]);
    const char* BsC = reinterpret_cast<const char*>(&Bs[cur][0]);
    #pragma unroll
    for (int kk = 0; kk < 2; ++kk) {
      short8 af[4], bfr[4];
      #pragma unroll
      for (int mi = 0; mi < 4; ++mi) {
        int row = wm*64 + mi*16 + (l & 15);
        int byte = row*128 + ((kk*64 + ((l >> 4) * 16)) ^ ((row & 7) << 4));
        af[mi] = *reinterpret_cast<const short8*>(AsC + byte);
      }
      #pragma unroll
      for (int ni = 0; ni < 4; ++ni) {
        int row = wn*64 + ni*16 + (l & 15);
        int byte = row*128 + ((kk*64 + ((l >> 4) * 16)) ^ ((row & 7) << 4));
        bfr[ni] = *reinterpret_cast<const short8*>(BsC + byte);
      }
      __builtin_amdgcn_s_setprio(1);
      #pragma unroll
      for (int mi = 0; mi < 4; ++mi)
        #pragma unroll
        for (int ni = 0; ni < 4; ++ni)
          acc[mi][ni] = __builtin_amdgcn_mfma_f32_16x16x32_bf16(af[mi], bfr[ni], acc[mi][ni], 0, 0, 0);
      __builtin_amdgcn_s_setprio(0);
    }
    cur ^= 1;
  }

  if (MODE == 0 && tn >= 2*EMB) {
    // ---- V block: transpose through LDS, emit VT[head][hd][n] ----
    ushort_t* T = &As[0][0];             // 1024 rowT x 16 els, 32KB
    #pragma unroll
    for (int mi = 0; mi < 4; ++mi) {
      #pragma unroll
      for (int ni = 0; ni < 4; ++ni) {
        #pragma unroll
        for (int r = 0; r < 4; ++r) {
          int rowl = wm*64 + mi*16 + ((l >> 4) * 4) + r;
          int coll = wn*64 + ni*16 + (l & 15);
          float v = acc[mi][ni][r] + bias[tn + coll];
          int b = rowl & 7, nloc = rowl >> 3;
          int hx = coll >> 6, hd = coll & 63;
          int rowT = (hx*8 + b)*64 + hd;
          int pc = (nloc >> 3) ^ (rowT & 1);
          T[rowT*16 + pc*8 + (nloc & 7)] = f2bf(v);
        }
      }
    }
    __syncthreads();
    const int hxg0 = (tn >> 6) & 7;
    #pragma unroll
    for (int i = 0; i < 8; ++i) {
      int c = i*256 + t;
      int rowT = c >> 1, lc = c & 1;
      int pc = lc ^ (rowT & 1);
      short8 val = *reinterpret_cast<const short8*>(&T[rowT*16 + pc*8]);
      int hx = rowT >> 9;
      int b  = (rowT >> 6) & 7;
      int hd = rowT & 63;
      int head = b*NHEAD + hxg0 + hx;
      size_t n = (size_t)(tm >> 3) + lc*8;
      *reinterpret_cast<short8*>(VTq + (size_t)head * HDIM * NSEQ + (size_t)hd * NSEQ + n) = val;
    }
    return;
  }

  #pragma unroll
  for (int mi = 0; mi < 4; ++mi) {
    #pragma unroll
    for (int ni = 0; ni < 4; ++ni) {
      #pragma unroll
      for (int r = 0; r < 4; ++r) {
        int row = tm + wm*64 + mi*16 + ((l >> 4) * 4) + r;
        int col = tn + wn*64 + ni*16 + (l & 15);
        float v = acc[mi][ni][r] + bias[col];
        if constexpr (MODE == 1) {
          Cf[(size_t)row * N + col] = v;
        } else {
          int w3 = col >> 9, hx = (col >> 6) & 7, hd = col & 63;
          int n = row >> 3, bb = row & 7;
          Cq[(size_t)w3 * ((size_t)NH_TOT * NSEQ * HDIM)
             + ((size_t)(bb * NHEAD + hx) * NSEQ + n) * HDIM + hd] = f2bf(v);
        }
      }
    }
  }
}

// ---------------- Flash attention (R12 structure + early K-fragment hoist) ----------------
#define CSC 0.18033688011112042f   /* (1/8) * log2(e) */

__global__ __launch_bounds__(256, 2) void attn_fwd(
    const ushort_t* __restrict__ Qb, const ushort_t* __restrict__ Kb,
    const ushort_t* __restrict__ VTb, ushort_t* __restrict__ Ob)
{
  __shared__ __align__(16) ushort_t Ks[2][2][64*64];
  __shared__ __align__(16) ushort_t Vs[2][2][64*64];
  const int t = threadIdx.x, w = t >> 6, l = t & 63;
  const int lq = l & 31, h = l >> 5;
  const int L = blockIdx.x + 8 * blockIdx.y;           // 0..511
  const int Tid = (L & 7) * 64 + (L >> 3);
  const int bh = Tid >> 3, qt = Tid & 7;
  const int b = bh >> 3, hh = bh & 7;
  const size_t hbase  = (size_t)bh * NSEQ * HDIM;
  const size_t vtbase = (size_t)bh * HDIM * NSEQ;
  const int qbase = qt*256 + w*64;

  short8 qreg[2][4];
  #pragma unroll
  for (int qb = 0; qb < 2; ++qb)
    #pragma unroll
    for (int kd = 0; kd < 4; ++kd) {
      short8 raw = *reinterpret_cast<const short8*>(
          Qb + hbase + (size_t)(qbase + qb*32 + lq) * HDIM + kd*16 + h*8);
      short8 q;
      #pragma unroll
      for (int e = 0; e < 8; ++e)
        q[e] = (short)f2bf(bf2f((ushort_t)raw[e]) * CSC);
      qreg[qb][kd] = q;
    }

  f32x16 Oacc[2][2] = {};     // [qb][dt]
  f32x16 lacc0 = {}, lacc1 = {};

  const short ONE = (short)0x3F80;  // bf16 1.0
  short8 ones = { ONE, ONE, ONE, ONE, ONE, ONE, ONE, ONE };

  const int srow = t >> 3;
  const int scol = (t & 7) * 8;
  const int c0 = scol ^ (SW(srow) << 3);
  const int c1 = scol ^ (SW(srow + 32) << 3);
  const ushort_t* Kg0 = Kb  + hbase  + (size_t)srow       * HDIM + c0;
  const ushort_t* Kg1 = Kb  + hbase  + (size_t)(srow+32)  * HDIM + c1;
  const ushort_t* Vg0 = VTb + vtbase + (size_t)srow       * NSEQ + c0;
  const ushort_t* Vg1 = VTb + vtbase + (size_t)(srow+32)  * NSEQ + c1;

  auto STAGE = [&](int bi, int p) {
    #pragma unroll
    for (int ss = 0; ss < 2; ++ss) {
      int kt = p*2 + ss;
      size_t ko = (size_t)kt * 64 * HDIM;
      int    vo = kt * 64;
      gll16(Kg0 + ko, &Ks[bi][ss][0]    + t*8);
      gll16(Kg1 + ko, &Ks[bi][ss][2048] + t*8);
      gll16(Vg0 + vo, &Vs[bi][ss][0]    + t*8);
      gll16(Vg1 + vo, &Vs[bi][ss][2048] + t*8);
    }
  };

  VMCNT0;
  STAGE(0, 0);

  int cur = 0;
  #pragma unroll 1
  for (int p = 0; p < NP; ++p) {
    VMCNT0;
    BAR;
    if (p + 1 < NP) STAGE(cur ^ 1, p + 1);

    // ---- hoisted K-fragment loads for BOTH subtiles (issue early) ----
    short8 kf[2][2][4];    // [ss][rp][kd]
    #pragma unroll
    for (int ss = 0; ss < 2; ++ss) {
      const char* KsC = reinterpret_cast<const char*>(&Ks[cur][ss][0]);
      #pragma unroll
      for (int rp = 0; rp < 2; ++rp) {
        int row = rp*32 + lq;
        int swr = SW(row) << 4;
        #pragma unroll
        for (int kd = 0; kd < 4; ++kd)
          kf[ss][rp][kd] = *reinterpret_cast<const short8*>(
              KsC + row*128 + ((kd*32 + h*16) ^ swr));
      }
    }

    #pragma unroll
    for (int ss = 0; ss < 2; ++ss) {
      const char* VsC = reinterpret_cast<const char*>(&Vs[cur][ss][0]);

      uint32 pa0[4][4], pa1[4][4];

      // ===== q-block 0: QK -> exp -> pack =====
      {
        f32x16 s0 = {}, s1 = {};
        __builtin_amdgcn_s_setprio(1);
        #pragma unroll
        for (int kd = 0; kd < 4; ++kd) {
          s0 = __builtin_amdgcn_mfma_f32_32x32x16_bf16(kf[ss][0][kd], qreg[0][kd], s0, 0, 0, 0);
          s1 = __builtin_amdgcn_mfma_f32_32x32x16_bf16(kf[ss][1][kd], qreg[0][kd], s1, 0, 0, 0);
        }
        __builtin_amdgcn_s_setprio(0);
        #pragma unroll
        for (int r = 0; r < 16; ++r) {
          s0[r] = __builtin_amdgcn_exp2f(s0[r]);
          s1[r] = __builtin_amdgcn_exp2f(s1[r]);
        }
        uint32 w0[8], w1[8];
        #pragma unroll
        for (int i = 0; i < 8; ++i) {
          float a0 = s0[2*i], b0 = s0[2*i+1];
          float a1 = s1[2*i], b1 = s1[2*i+1];
          asm("v_cvt_pk_bf16_f32 %0, %1, %2" : "=v"(w0[i]) : "v"(a0), "v"(b0));
          asm("v_cvt_pk_bf16_f32 %0, %1, %2" : "=v"(w1[i]) : "v"(a1), "v"(b1));
        }
        #pragma unroll
        for (int sg = 0; sg < 2; ++sg) {
          uint32 a, bb;
          a = w0[4*sg+0]; bb = w0[4*sg+2];
          asm("v_permlane32_swap_b32 %0, %1" : "+v"(a), "+v"(bb));
          pa0[sg][0] = a; pa0[sg][2] = bb;
          a = w0[4*sg+1]; bb = w0[4*sg+3];
          asm("v_permlane32_swap_b32 %0, %1" : "+v"(a), "+v"(bb));
          pa0[sg][1] = a; pa0[sg][3] = bb;
          a = w1[4*sg+0]; bb = w1[4*sg+2];
          asm("v_permlane32_swap_b32 %0, %1" : "+v"(a), "+v"(bb));
          pa0[2+sg][0] = a; pa0[2+sg][2] = bb;
          a = w1[4*sg+1]; bb = w1[4*sg+3];
          asm("v_permlane32_swap_b32 %0, %1" : "+v"(a), "+v"(bb));
          pa0[2+sg][1] = a; pa0[2+sg][3] = bb;
        }
      }

      // ===== q-block 1 =====
      {
        f32x16 s0 = {}, s1 = {};
        __builtin_amdgcn_s_setprio(1);
        #pragma unroll
        for (int kd = 0; kd < 4; ++kd) {
          s0 = __builtin_amdgcn_mfma_f32_32x32x16_bf16(kf[ss][0][kd], qreg[1][kd], s0, 0, 0, 0);
          s1 = __builtin_amdgcn_mfma_f32_32x32x16_bf16(kf[ss][1][kd], qreg[1][kd], s1, 0, 0, 0);
        }
        __builtin_amdgcn_s_setprio(0);
        #pragma unroll
        for (int r = 0; r < 16; ++r) {
          s0[r] = __builtin_amdgcn_exp2f(s0[r]);
          s1[r] = __builtin_amdgcn_exp2f(s1[r]);
        }
        uint32 w0[8], w1[8];
        #pragma unroll
        for (int i = 0; i < 8; ++i) {
          float a0 = s0[2*i], b0 = s0[2*i+1];
          float a1 = s1[2*i], b1 = s1[2*i+1];
          asm("v_cvt_pk_bf16_f32 %0, %1, %2" : "=v"(w0[i]) : "v"(a0), "v"(b0));
          asm("v_cvt_pk_bf16_f32 %0, %1, %2" : "=v"(w1[i]) : "v"(a1), "v"(b1));
        }
        #pragma unroll
        for (int sg = 0; sg < 2; ++sg) {
          uint32 a, bb;
          a = w0[4*sg+0]; bb = w0[4*sg+2];
          asm("v_permlane32_swap_b32 %0, %1" : "+v"(a), "+v"(bb));
          pa1[sg][0] = a; pa1[sg][2] = bb;
          a = w0[4*sg+1]; bb = w0[4*sg+3];
          asm("v_permlane32_swap_b32 %0, %1" : "+v"(a), "+v"(bb));
          pa1[sg][1] = a; pa1[sg][3] = bb;
          a = w1[4*sg+0]; bb = w1[4*sg+2];
          asm("v_permlane32_swap_b32 %0, %1" : "+v"(a), "+v"(bb));
          pa1[2+sg][0] = a; pa1[2+sg][2] = bb;
          a = w1[4*sg+1]; bb = w1[4*sg+3];
          asm("v_permlane32_swap_b32 %0, %1" : "+v"(a), "+v"(bb));
          pa1[2+sg][1] = a; pa1[2+sg][3] = bb;
        }
      }

      short8 vf[2][4];
      #pragma unroll
      for (int dt = 0; dt < 2; ++dt) {
        int d = dt*32 + lq;
        int swd = SW(d) << 4;
        #pragma unroll
        for (int km = 0; km < 4; ++km)
          vf[dt][km] = *reinterpret_cast<const short8*>(
              VsC + d*128 + ((km*32 + h*16) ^ swd));
      }

      __builtin_amdgcn_s_setprio(1);
      #pragma unroll
      for (int km = 0; km < 4; ++km) {
        uint4v u0; u0[0] = pa0[km][0]; u0[1] = pa0[km][1]; u0[2] = pa0[km][2]; u0[3] = pa0[km][3];
        short8 paf0 = __builtin_bit_cast(short8, u0);
        uint4v u1; u1[0] = pa1[km][0]; u1[1] = pa1[km][1]; u1[2] = pa1[km][2]; u1[3] = pa1[km][3];
        short8 paf1 = __builtin_bit_cast(short8, u1);
        Oacc[0][0] = __builtin_amdgcn_mfma_f32_32x32x16_bf16(paf0, vf[0][km], Oacc[0][0], 0, 0, 0);
        lacc0      = __builtin_amdgcn_mfma_f32_32x32x16_bf16(paf0, ones,     lacc0,      0, 0, 0);
        Oacc[0][1] = __builtin_amdgcn_mfma_f32_32x32x16_bf16(paf0, vf[1][km], Oacc[0][1], 0, 0, 0);
        Oacc[1][0] = __builtin_amdgcn_mfma_f32_32x32x16_bf16(paf1, vf[0][km], Oacc[1][0], 0, 0, 0);
        lacc1      = __builtin_amdgcn_mfma_f32_32x32x16_bf16(paf1, ones,     lacc1,      0, 0, 0);
        Oacc[1][1] = __builtin_amdgcn_mfma_f32_32x32x16_bf16(paf1, vf[1][km], Oacc[1][1], 0, 0, 0);
      }
      __builtin_amdgcn_s_setprio(0);
    }

    cur ^= 1;
  }

  #pragma unroll
  for (int r = 0; r < 16; ++r) {
    int qrow = (r & 3) + 8*(r >> 2) + 4*h;
    float li0 = __builtin_amdgcn_rcpf(lacc0[r]);
    float li1 = __builtin_amdgcn_rcpf(lacc1[r]);
    #pragma unroll
    for (int dt = 0; dt < 2; ++dt) {
      int d = dt*32 + lq;
      int n0 = qbase + qrow;
      int n1 = qbase + 32 + qrow;
      Ob[((size_t)n0 * BSZ + b) * EMB + hh*64 + d] = f2bf(Oacc[0][dt][r] * li0);
      Ob[((size_t)n1 * BSZ + b) * EMB + hh*64 + d] = f2bf(Oacc[1][dt][r] * li1);
    }
  }
}

extern "C" void kernel_launch(void* const* d_in, const int* in_sizes, int n_in,
                              void* d_out, int out_size, void* d_ws, size_t ws_size,
                              hipStream_t stream) {
  (void)in_sizes; (void)n_in; (void)out_size; (void)ws_size;
  const float* seq  = (const float*)d_in[0];
  const float* Wqkv = (const float*)d_in[1];
  const float* bqkv = (const float*)d_in[2];
  const float* Wout = (const float*)d_in[3];
  const float* bout = (const float*)d_in[4];
  float* out = (float*)d_out;

  ushort_t* seq_bf  = (ushort_t*)d_ws;
  ushort_t* wqkv_bf = seq_bf  + (size_t)MTOK * EMB;
  ushort_t* wout_bf = wqkv_bf + (size_t)3 * EMB * EMB;
  ushort_t* qkvbuf  = wout_bf + (size_t)EMB * EMB;
  ushort_t* vtbuf   = qkvbuf  + (size_t)3 * NH_TOT * NSEQ * HDIM;
  // attn output aliases the (unwritten) V region of qkvbuf
  ushort_t* attno   = qkvbuf  + (size_t)2 * NH_TOT * NSEQ * HDIM;

  const int na8 = MTOK*EMB/8, nb8 = 3*EMB*EMB/8, nc8 = EMB*EMB/8;
  cvt3<<<2048, 256, 0, stream>>>(
      seq, seq_bf, na8, Wqkv, wqkv_bf, nb8, Wout, wout_bf, nc8);

  gemm_bt<0><<<dim3(12, 128), 256, 0, stream>>>(seq_bf, wqkv_bf, bqkv, nullptr, qkvbuf,
                                                vtbuf, MTOK, 3*EMB, EMB);

  const ushort_t* Qb  = qkvbuf;
  const ushort_t* Kb  = qkvbuf + (size_t)NH_TOT * NSEQ * HDIM;

  attn_fwd<<<dim3(8, 64), 256, 0, stream>>>(Qb, Kb, vtbuf, attno);

  gemm_bt<1><<<dim3(4, 128), 256, 0, stream>>>(attno, wout_bf, bout, out, nullptr,
                                               nullptr, MTOK, EMB, EMB);
}

// Round 18
// 157.003 us; speedup vs baseline: 1.0037x; 1.0037x over previous
//
#include <hip/hip_runtime.h>
#include <stdint.h>

typedef unsigned short ushort_t;
typedef unsigned int uint32;
typedef __attribute__((ext_vector_type(8))) short short8;
typedef __attribute__((ext_vector_type(4))) float f32x4;
typedef __attribute__((ext_vector_type(16))) float f32x16;
typedef __attribute__((ext_vector_type(4))) uint32 uint4v;

#define NSEQ 2048
#define BSZ 8
#define EMB 512
#define NHEAD 8
#define HDIM 64
#define MTOK (NSEQ*BSZ)      // 16384
#define NH_TOT (BSZ*NHEAD)   // 64
#define NP (NSEQ/128)        // 16 KV tile-pairs

#define VMCNT0 asm volatile("s_waitcnt vmcnt(0)" ::: "memory")
#define BAR __builtin_amdgcn_s_barrier()

__device__ __forceinline__ ushort_t f2bf(float f) {
  uint32_t u = __builtin_bit_cast(uint32_t, f);
  u += 0x7FFFu + ((u >> 16) & 1u);
  return (ushort_t)(u >> 16);
}
__device__ __forceinline__ float bf2f(ushort_t u) {
  uint32_t x = ((uint32_t)u) << 16;
  return __builtin_bit_cast(float, x);
}

__device__ __forceinline__ void gll16(const void* g, void* l) {
  __builtin_amdgcn_global_load_lds(
      (const __attribute__((address_space(1))) void*)g,
      (__attribute__((address_space(3))) void*)l, 16, 0, 0);
}

// swizzle slot for row r (8 slots of 16B within a 128B row)
__device__ __forceinline__ int SW(int r) { return (r & 7) ^ ((r >> 3) & 7); }

// ---------------- f32 -> bf16 convert (fused x3, grid-stride, 32B/iter) ----------------
__global__ void cvt3(const float* __restrict__ a, ushort_t* __restrict__ oa, int na8,
                     const float* __restrict__ b, ushort_t* __restrict__ ob, int nb8,
                     const float* __restrict__ c, ushort_t* __restrict__ oc, int nc8) {
  const int total = na8 + nb8 + nc8;
  const int stride = gridDim.x * blockDim.x;
  for (int i = blockIdx.x * blockDim.x + threadIdx.x; i < total; i += stride) {
    const float* src; ushort_t* dst; int j = i;
    if (j < na8) { src = a; dst = oa; }
    else {
      j -= na8;
      if (j < nb8) { src = b; dst = ob; }
      else { j -= nb8; src = c; dst = oc; }
    }
    float4 v0 = reinterpret_cast<const float4*>(src)[j*2];
    float4 v1 = reinterpret_cast<const float4*>(src)[j*2+1];
    union { ushort_t u[8]; uint4 q; } o;
    o.u[0] = f2bf(v0.x); o.u[1] = f2bf(v0.y); o.u[2] = f2bf(v0.z); o.u[3] = f2bf(v0.w);
    o.u[4] = f2bf(v1.x); o.u[5] = f2bf(v1.y); o.u[6] = f2bf(v1.z); o.u[7] = f2bf(v1.w);
    reinterpret_cast<uint4*>(dst)[j] = o.q;
  }
}

// ---------------- GEMM: C[M,N] = A[M,K] * B[N,K]^T + bias ----------------
// 128x128 tile, XCD-chunked swizzle, single-barrier counted pipeline.
// MODE 0: Q/K scalar scatter to [w3][head][n][hd]; V blocks (tn>=1024) -> VT[head][hd][n].
// MODE 1: f32 output.
template<int MODE>
__global__ __launch_bounds__(256, 2) void gemm_bt(
    const ushort_t* __restrict__ A, const ushort_t* __restrict__ B,
    const float* __restrict__ bias,
    float* __restrict__ Cf, ushort_t* __restrict__ Cq, ushort_t* __restrict__ VTq,
    int M, int N, int K)
{
  __shared__ __align__(16) ushort_t As[2][128*64];
  __shared__ __align__(16) ushort_t Bs[2][128*64];
  const int t = threadIdx.x;
  const int w = t >> 6, l = t & 63;

  const int nbx = gridDim.x;
  const int bid = blockIdx.x + nbx * blockIdx.y;
  const int per = (nbx * gridDim.y) >> 3;
  const int swz = (bid & 7) * per + (bid >> 3);
  const int tm = (swz / nbx) * 128, tn = (swz % nbx) * 128;
  const int wm = w >> 1, wn = w & 1;

  f32x4 acc[4][4] = {};

  auto STAGE = [&](int buf, int k0) {
    #pragma unroll
    for (int j = 0; j < 4; ++j) {
      int row = j*32 + w*8 + (l >> 3);
      int cole = ((l & 7) * 8) ^ ((row & 7) << 3);
      gll16(A + (size_t)(tm + row) * K + k0 + cole, &As[buf][0] + j*2048 + w*512 + l*8);
      gll16(B + (size_t)(tn + row) * K + k0 + cole, &Bs[buf][0] + j*2048 + w*512 + l*8);
    }
  };

  const int NK = K >> 6;                 // 8 for K=512
  STAGE(0, 0);

  int cur = 0;
  #pragma unroll 1
  for (int k = 0; k < NK; ++k) {
    VMCNT0;                              // own stage loads for tile k landed
    BAR;                                 // all waves staged k AND done reading buf[cur^1]
    if (k + 1 < NK) STAGE(cur ^ 1, (k + 1) << 6);

    const char* AsC = reinterpret_cast<const char*>(&As[cur][0]);
    const char* BsC = reinterpret_cast<const char*>(&Bs[cur][0]);
    #pragma unroll
    for (int kk = 0; kk < 2; ++kk) {
      short8 af[4], bfr[4];
      #pragma unroll
      for (int mi = 0; mi < 4; ++mi) {
        int row = wm*64 + mi*16 + (l & 15);
        int byte = row*128 + ((kk*64 + ((l >> 4) * 16)) ^ ((row & 7) << 4));
        af[mi] = *reinterpret_cast<const short8*>(AsC + byte);
      }
      #pragma unroll
      for (int ni = 0; ni < 4; ++ni) {
        int row = wn*64 + ni*16 + (l & 15);
        int byte = row*128 + ((kk*64 + ((l >> 4) * 16)) ^ ((row & 7) << 4));
        bfr[ni] = *reinterpret_cast<const short8*>(BsC + byte);
      }
      __builtin_amdgcn_s_setprio(1);
      #pragma unroll
      for (int mi = 0; mi < 4; ++mi)
        #pragma unroll
        for (int ni = 0; ni < 4; ++ni)
          acc[mi][ni] = __builtin_amdgcn_mfma_f32_16x16x32_bf16(af[mi], bfr[ni], acc[mi][ni], 0, 0, 0);
      __builtin_amdgcn_s_setprio(0);
    }
    cur ^= 1;
  }

  if (MODE == 0 && tn >= 2*EMB) {
    // ---- V block: transpose through LDS, emit VT[head][hd][n] ----
    ushort_t* T = &As[0][0];             // 1024 rowT x 16 els, 32KB
    #pragma unroll
    for (int mi = 0; mi < 4; ++mi) {
      #pragma unroll
      for (int ni = 0; ni < 4; ++ni) {
        #pragma unroll
        for (int r = 0; r < 4; ++r) {
          int rowl = wm*64 + mi*16 + ((l >> 4) * 4) + r;
          int coll = wn*64 + ni*16 + (l & 15);
          float v = acc[mi][ni][r] + bias[tn + coll];
          int b = rowl & 7, nloc = rowl >> 3;
          int hx = coll >> 6, hd = coll & 63;
          int rowT = (hx*8 + b)*64 + hd;
          int pc = (nloc >> 3) ^ (rowT & 1);
          T[rowT*16 + pc*8 + (nloc & 7)] = f2bf(v);
        }
      }
    }
    __syncthreads();
    const int hxg0 = (tn >> 6) & 7;
    #pragma unroll
    for (int i = 0; i < 8; ++i) {
      int c = i*256 + t;
      int rowT = c >> 1, lc = c & 1;
      int pc = lc ^ (rowT & 1);
      short8 val = *reinterpret_cast<const short8*>(&T[rowT*16 + pc*8]);
      int hx = rowT >> 9;
      int b  = (rowT >> 6) & 7;
      int hd = rowT & 63;
      int head = b*NHEAD + hxg0 + hx;
      size_t n = (size_t)(tm >> 3) + lc*8;
      *reinterpret_cast<short8*>(VTq + (size_t)head * HDIM * NSEQ + (size_t)hd * NSEQ + n) = val;
    }
    return;
  }

  #pragma unroll
  for (int mi = 0; mi < 4; ++mi) {
    #pragma unroll
    for (int ni = 0; ni < 4; ++ni) {
      #pragma unroll
      for (int r = 0; r < 4; ++r) {
        int row = tm + wm*64 + mi*16 + ((l >> 4) * 4) + r;
        int col = tn + wn*64 + ni*16 + (l & 15);
        float v = acc[mi][ni][r] + bias[col];
        if constexpr (MODE == 1) {
          Cf[(size_t)row * N + col] = v;
        } else {
          int w3 = col >> 9, hx = (col >> 6) & 7, hd = col & 63;
          int n = row >> 3, bb = row & 7;
          Cq[(size_t)w3 * ((size_t)NH_TOT * NSEQ * HDIM)
             + ((size_t)(bb * NHEAD + hx) * NSEQ + n) * HDIM + hd] = f2bf(v);
        }
      }
    }
  }
}

// ---------------- Flash attention (R12 structure + early K-fragment hoist) ----------------
#define CSC 0.18033688011112042f   /* (1/8) * log2(e) */

__global__ __launch_bounds__(256, 2) void attn_fwd(
    const ushort_t* __restrict__ Qb, const ushort_t* __restrict__ Kb,
    const ushort_t* __restrict__ VTb, ushort_t* __restrict__ Ob)
{
  __shared__ __align__(16) ushort_t Ks[2][2][64*64];
  __shared__ __align__(16) ushort_t Vs[2][2][64*64];
  const int t = threadIdx.x, w = t >> 6, l = t & 63;
  const int lq = l & 31, h = l >> 5;
  const int L = blockIdx.x + 8 * blockIdx.y;           // 0..511
  const int Tid = (L & 7) * 64 + (L >> 3);
  const int bh = Tid >> 3, qt = Tid & 7;
  const int b = bh >> 3, hh = bh & 7;
  const size_t hbase  = (size_t)bh * NSEQ * HDIM;
  const size_t vtbase = (size_t)bh * HDIM * NSEQ;
  const int qbase = qt*256 + w*64;

  short8 qreg[2][4];
  #pragma unroll
  for (int qb = 0; qb < 2; ++qb)
    #pragma unroll
    for (int kd = 0; kd < 4; ++kd) {
      short8 raw = *reinterpret_cast<const short8*>(
          Qb + hbase + (size_t)(qbase + qb*32 + lq) * HDIM + kd*16 + h*8);
      short8 q;
      #pragma unroll
      for (int e = 0; e < 8; ++e)
        q[e] = (short)f2bf(bf2f((ushort_t)raw[e]) * CSC);
      qreg[qb][kd] = q;
    }

  f32x16 Oacc[2][2] = {};     // [qb][dt]
  f32x16 lacc0 = {}, lacc1 = {};

  const short ONE = (short)0x3F80;  // bf16 1.0
  short8 ones = { ONE, ONE, ONE, ONE, ONE, ONE, ONE, ONE };

  const int srow = t >> 3;
  const int scol = (t & 7) * 8;
  const int c0 = scol ^ (SW(srow) << 3);
  const int c1 = scol ^ (SW(srow + 32) << 3);
  const ushort_t* Kg0 = Kb  + hbase  + (size_t)srow       * HDIM + c0;
  const ushort_t* Kg1 = Kb  + hbase  + (size_t)(srow+32)  * HDIM + c1;
  const ushort_t* Vg0 = VTb + vtbase + (size_t)srow       * NSEQ + c0;
  const ushort_t* Vg1 = VTb + vtbase + (size_t)(srow+32)  * NSEQ + c1;

  auto STAGE = [&](int bi, int p) {
    #pragma unroll
    for (int ss = 0; ss < 2; ++ss) {
      int kt = p*2 + ss;
      size_t ko = (size_t)kt * 64 * HDIM;
      int    vo = kt * 64;
      gll16(Kg0 + ko, &Ks[bi][ss][0]    + t*8);
      gll16(Kg1 + ko, &Ks[bi][ss][2048] + t*8);
      gll16(Vg0 + vo, &Vs[bi][ss][0]    + t*8);
      gll16(Vg1 + vo, &Vs[bi][ss][2048] + t*8);
    }
  };

  VMCNT0;
  STAGE(0, 0);

  int cur = 0;
  #pragma unroll 1
  for (int p = 0; p < NP; ++p) {
    VMCNT0;
    BAR;
    if (p + 1 < NP) STAGE(cur ^ 1, p + 1);

    // ---- hoisted K-fragment loads for BOTH subtiles (issue early) ----
    short8 kf[2][2][4];    // [ss][rp][kd]
    #pragma unroll
    for (int ss = 0; ss < 2; ++ss) {
      const char* KsC = reinterpret_cast<const char*>(&Ks[cur][ss][0]);
      #pragma unroll
      for (int rp = 0; rp < 2; ++rp) {
        int row = rp*32 + lq;
        int swr = SW(row) << 4;
        #pragma unroll
        for (int kd = 0; kd < 4; ++kd)
          kf[ss][rp][kd] = *reinterpret_cast<const short8*>(
              KsC + row*128 + ((kd*32 + h*16) ^ swr));
      }
    }

    #pragma unroll
    for (int ss = 0; ss < 2; ++ss) {
      const char* VsC = reinterpret_cast<const char*>(&Vs[cur][ss][0]);

      uint32 pa0[4][4], pa1[4][4];

      // ===== q-block 0: QK -> exp -> pack =====
      {
        f32x16 s0 = {}, s1 = {};
        __builtin_amdgcn_s_setprio(1);
        #pragma unroll
        for (int kd = 0; kd < 4; ++kd) {
          s0 = __builtin_amdgcn_mfma_f32_32x32x16_bf16(kf[ss][0][kd], qreg[0][kd], s0, 0, 0, 0);
          s1 = __builtin_amdgcn_mfma_f32_32x32x16_bf16(kf[ss][1][kd], qreg[0][kd], s1, 0, 0, 0);
        }
        __builtin_amdgcn_s_setprio(0);
        #pragma unroll
        for (int r = 0; r < 16; ++r) {
          s0[r] = __builtin_amdgcn_exp2f(s0[r]);
          s1[r] = __builtin_amdgcn_exp2f(s1[r]);
        }
        uint32 w0[8], w1[8];
        #pragma unroll
        for (int i = 0; i < 8; ++i) {
          float a0 = s0[2*i], b0 = s0[2*i+1];
          float a1 = s1[2*i], b1 = s1[2*i+1];
          asm("v_cvt_pk_bf16_f32 %0, %1, %2" : "=v"(w0[i]) : "v"(a0), "v"(b0));
          asm("v_cvt_pk_bf16_f32 %0, %1, %2" : "=v"(w1[i]) : "v"(a1), "v"(b1));
        }
        #pragma unroll
        for (int sg = 0; sg < 2; ++sg) {
          uint32 a, bb;
          a = w0[4*sg+0]; bb = w0[4*sg+2];
          asm("v_permlane32_swap_b32 %0, %1" : "+v"(a), "+v"(bb));
          pa0[sg][0] = a; pa0[sg][2] = bb;
          a = w0[4*sg+1]; bb = w0[4*sg+3];
          asm("v_permlane32_swap_b32 %0, %1" : "+v"(a), "+v"(bb));
          pa0[sg][1] = a; pa0[sg][3] = bb;
          a = w1[4*sg+0]; bb = w1[4*sg+2];
          asm("v_permlane32_swap_b32 %0, %1" : "+v"(a), "+v"(bb));
          pa0[2+sg][0] = a; pa0[2+sg][2] = bb;
          a = w1[4*sg+1]; bb = w1[4*sg+3];
          asm("v_permlane32_swap_b32 %0, %1" : "+v"(a), "+v"(bb));
          pa0[2+sg][1] = a; pa0[2+sg][3] = bb;
        }
      }

      // ===== q-block 1 =====
      {
        f32x16 s0 = {}, s1 = {};
        __builtin_amdgcn_s_setprio(1);
        #pragma unroll
        for (int kd = 0; kd < 4; ++kd) {
          s0 = __builtin_amdgcn_mfma_f32_32x32x16_bf16(kf[ss][0][kd], qreg[1][kd], s0, 0, 0, 0);
          s1 = __builtin_amdgcn_mfma_f32_32x32x16_bf16(kf[ss][1][kd], qreg[1][kd], s1, 0, 0, 0);
        }
        __builtin_amdgcn_s_setprio(0);
        #pragma unroll
        for (int r = 0; r < 16; ++r) {
          s0[r] = __builtin_amdgcn_exp2f(s0[r]);
          s1[r] = __builtin_amdgcn_exp2f(s1[r]);
        }
        uint32 w0[8], w1[8];
        #pragma unroll
        for (int i = 0; i < 8; ++i) {
          float a0 = s0[2*i], b0 = s0[2*i+1];
          float a1 = s1[2*i], b1 = s1[2*i+1];
          asm("v_cvt_pk_bf16_f32 %0, %1, %2" : "=v"(w0[i]) : "v"(a0), "v"(b0));
          asm("v_cvt_pk_bf16_f32 %0, %1, %2" : "=v"(w1[i]) : "v"(a1), "v"(b1));
        }
        #pragma unroll
        for (int sg = 0; sg < 2; ++sg) {
          uint32 a, bb;
          a = w0[4*sg+0]; bb = w0[4*sg+2];
          asm("v_permlane32_swap_b32 %0, %1" : "+v"(a), "+v"(bb));
          pa1[sg][0] = a; pa1[sg][2] = bb;
          a = w0[4*sg+1]; bb = w0[4*sg+3];
          asm("v_permlane32_swap_b32 %0, %1" : "+v"(a), "+v"(bb));
          pa1[sg][1] = a; pa1[sg][3] = bb;
          a = w1[4*sg+0]; bb = w1[4*sg+2];
          asm("v_permlane32_swap_b32 %0, %1" : "+v"(a), "+v"(bb));
          pa1[2+sg][0] = a; pa1[2+sg][2] = bb;
          a = w1[4*sg+1]; bb = w1[4*sg+3];
          asm("v_permlane32_swap_b32 %0, %1" : "+v"(a), "+v"(bb));
          pa1[2+sg][1] = a; pa1[2+sg][3] = bb;
        }
      }

      short8 vf[2][4];
      #pragma unroll
      for (int dt = 0; dt < 2; ++dt) {
        int d = dt*32 + lq;
        int swd = SW(d) << 4;
        #pragma unroll
        for (int km = 0; km < 4; ++km)
          vf[dt][km] = *reinterpret_cast<const short8*>(
              VsC + d*128 + ((km*32 + h*16) ^ swd));
      }

      __builtin_amdgcn_s_setprio(1);
      #pragma unroll
      for (int km = 0; km < 4; ++km) {
        uint4v u0; u0[0] = pa0[km][0]; u0[1] = pa0[km][1]; u0[2] = pa0[km][2]; u0[3] = pa0[km][3];
        short8 paf0 = __builtin_bit_cast(short8, u0);
        uint4v u1; u1[0] = pa1[km][0]; u1[1] = pa1[km][1]; u1[2] = pa1[km][2]; u1[3] = pa1[km][3];
        short8 paf1 = __builtin_bit_cast(short8, u1);
        Oacc[0][0] = __builtin_amdgcn_mfma_f32_32x32x16_bf16(paf0, vf[0][km], Oacc[0][0], 0, 0, 0);
        lacc0      = __builtin_amdgcn_mfma_f32_32x32x16_bf16(paf0, ones,     lacc0,      0, 0, 0);
        Oacc[0][1] = __builtin_amdgcn_mfma_f32_32x32x16_bf16(paf0, vf[1][km], Oacc[0][1], 0, 0, 0);
        Oacc[1][0] = __builtin_amdgcn_mfma_f32_32x32x16_bf16(paf1, vf[0][km], Oacc[1][0], 0, 0, 0);
        lacc1      = __builtin_amdgcn_mfma_f32_32x32x16_bf16(paf1, ones,     lacc1,      0, 0, 0);
        Oacc[1][1] = __builtin_amdgcn_mfma_f32_32x32x16_bf16(paf1, vf[1][km], Oacc[1][1], 0, 0, 0);
      }
      __builtin_amdgcn_s_setprio(0);
    }

    cur ^= 1;
  }

  #pragma unroll
  for (int r = 0; r < 16; ++r) {
    int qrow = (r & 3) + 8*(r >> 2) + 4*h;
    float li0 = __builtin_amdgcn_rcpf(lacc0[r]);
    float li1 = __builtin_amdgcn_rcpf(lacc1[r]);
    #pragma unroll
    for (int dt = 0; dt < 2; ++dt) {
      int d = dt*32 + lq;
      int n0 = qbase + qrow;
      int n1 = qbase + 32 + qrow;
      Ob[((size_t)n0 * BSZ + b) * EMB + hh*64 + d] = f2bf(Oacc[0][dt][r] * li0);
      Ob[((size_t)n1 * BSZ + b) * EMB + hh*64 + d] = f2bf(Oacc[1][dt][r] * li1);
    }
  }
}

extern "C" void kernel_launch(void* const* d_in, const int* in_sizes, int n_in,
                              void* d_out, int out_size, void* d_ws, size_t ws_size,
                              hipStream_t stream) {
  (void)in_sizes; (void)n_in; (void)out_size; (void)ws_size;
  const float* seq  = (const float*)d_in[0];
  const float* Wqkv = (const float*)d_in[1];
  const float* bqkv = (const float*)d_in[2];
  const float* Wout = (const float*)d_in[3];
  const float* bout = (const float*)d_in[4];
  float* out = (float*)d_out;

  ushort_t* seq_bf  = (ushort_t*)d_ws;
  ushort_t* wqkv_bf = seq_bf  + (size_t)MTOK * EMB;
  ushort_t* wout_bf = wqkv_bf + (size_t)3 * EMB * EMB;
  ushort_t* qkvbuf  = wout_bf + (size_t)EMB * EMB;
  ushort_t* vtbuf   = qkvbuf  + (size_t)3 * NH_TOT * NSEQ * HDIM;
  // attn output aliases the (unwritten) V region of qkvbuf
  ushort_t* attno   = qkvbuf  + (size_t)2 * NH_TOT * NSEQ * HDIM;

  const int na8 = MTOK*EMB/8, nb8 = 3*EMB*EMB/8, nc8 = EMB*EMB/8;
  cvt3<<<2048, 256, 0, stream>>>(
      seq, seq_bf, na8, Wqkv, wqkv_bf, nb8, Wout, wout_bf, nc8);

  gemm_bt<0><<<dim3(12, 128), 256, 0, stream>>>(seq_bf, wqkv_bf, bqkv, nullptr, qkvbuf,
                                                vtbuf, MTOK, 3*EMB, EMB);

  const ushort_t* Qb  = qkvbuf;
  const ushort_t* Kb  = qkvbuf + (size_t)NH_TOT * NSEQ * HDIM;

  attn_fwd<<<dim3(8, 64), 256, 0, stream>>>(Qb, Kb, vtbuf, attno);

  gemm_bt<1><<<dim3(4, 128), 256, 0, stream>>>(attno, wout_bf, bout, out, nullptr,
                                               nullptr, MTOK, EMB, EMB);
}

// Round 19
// 149.176 us; speedup vs baseline: 1.0563x; 1.0525x over previous
//
#include <hip/hip_runtime.h>
#include <stdint.h>

typedef unsigned short ushort_t;
typedef unsigned int uint32;
typedef __attribute__((ext_vector_type(8))) short short8;
typedef __attribute__((ext_vector_type(4))) float f32x4;
typedef __attribute__((ext_vector_type(16))) float f32x16;
typedef __attribute__((ext_vector_type(4))) uint32 uint4v;

#define NSEQ 2048
#define BSZ 8
#define EMB 512
#define NHEAD 8
#define HDIM 64
#define MTOK (NSEQ*BSZ)      // 16384
#define NH_TOT (BSZ*NHEAD)   // 64
#define NP (NSEQ/128)        // 16 KV tile-pairs

#define VMCNT0 asm volatile("s_waitcnt vmcnt(0)" ::: "memory")
#define BAR __builtin_amdgcn_s_barrier()

__device__ __forceinline__ ushort_t f2bf(float f) {
  uint32_t u = __builtin_bit_cast(uint32_t, f);
  u += 0x7FFFu + ((u >> 16) & 1u);
  return (ushort_t)(u >> 16);
}
__device__ __forceinline__ float bf2f(ushort_t u) {
  uint32_t x = ((uint32_t)u) << 16;
  return __builtin_bit_cast(float, x);
}

__device__ __forceinline__ void gll16(const void* g, void* l) {
  __builtin_amdgcn_global_load_lds(
      (const __attribute__((address_space(1))) void*)g,
      (__attribute__((address_space(3))) void*)l, 16, 0, 0);
}

// swizzle slot for row r (8 slots of 16B within a 128B row)
__device__ __forceinline__ int SW(int r) { return (r & 7) ^ ((r >> 3) & 7); }

// ---------------- f32 -> bf16 convert (fused x3, grid-stride, 32B/iter) ----------------
__global__ void cvt3(const float* __restrict__ a, ushort_t* __restrict__ oa, int na8,
                     const float* __restrict__ b, ushort_t* __restrict__ ob, int nb8,
                     const float* __restrict__ c, ushort_t* __restrict__ oc, int nc8) {
  const int total = na8 + nb8 + nc8;
  const int stride = gridDim.x * blockDim.x;
  for (int i = blockIdx.x * blockDim.x + threadIdx.x; i < total; i += stride) {
    const float* src; ushort_t* dst; int j = i;
    if (j < na8) { src = a; dst = oa; }
    else {
      j -= na8;
      if (j < nb8) { src = b; dst = ob; }
      else { j -= nb8; src = c; dst = oc; }
    }
    float4 v0 = reinterpret_cast<const float4*>(src)[j*2];
    float4 v1 = reinterpret_cast<const float4*>(src)[j*2+1];
    union { ushort_t u[8]; uint4 q; } o;
    o.u[0] = f2bf(v0.x); o.u[1] = f2bf(v0.y); o.u[2] = f2bf(v0.z); o.u[3] = f2bf(v0.w);
    o.u[4] = f2bf(v1.x); o.u[5] = f2bf(v1.y); o.u[6] = f2bf(v1.z); o.u[7] = f2bf(v1.w);
    reinterpret_cast<uint4*>(dst)[j] = o.q;
  }
}

// ---------------- GEMM: C[M,N] = A[M,K] * B[N,K]^T + bias ----------------
// 128x128 tile, XCD-chunked swizzle, single-barrier counted pipeline.
// MODE 0: Q/K scalar scatter to [w3][head][n][hd]; V blocks (tn>=1024) -> VT[head][hd][n].
// MODE 1: f32 output.
template<int MODE>
__global__ __launch_bounds__(256, 2) void gemm_bt(
    const ushort_t* __restrict__ A, const ushort_t* __restrict__ B,
    const float* __restrict__ bias,
    float* __restrict__ Cf, ushort_t* __restrict__ Cq, ushort_t* __restrict__ VTq,
    int M, int N, int K)
{
  __shared__ __align__(16) ushort_t As[2][128*64];
  __shared__ __align__(16) ushort_t Bs[2][128*64];
  const int t = threadIdx.x;
  const int w = t >> 6, l = t & 63;

  const int nbx = gridDim.x;
  const int bid = blockIdx.x + nbx * blockIdx.y;
  const int per = (nbx * gridDim.y) >> 3;
  const int swz = (bid & 7) * per + (bid >> 3);
  const int tm = (swz / nbx) * 128, tn = (swz % nbx) * 128;
  const int wm = w >> 1, wn = w & 1;

  f32x4 acc[4][4] = {};

  auto STAGE = [&](int buf, int k0) {
    #pragma unroll
    for (int j = 0; j < 4; ++j) {
      int row = j*32 + w*8 + (l >> 3);
      int cole = ((l & 7) * 8) ^ ((row & 7) << 3);
      gll16(A + (size_t)(tm + row) * K + k0 + cole, &As[buf][0] + j*2048 + w*512 + l*8);
      gll16(B + (size_t)(tn + row) * K + k0 + cole, &Bs[buf][0] + j*2048 + w*512 + l*8);
    }
  };

  const int NK = K >> 6;                 // 8 for K=512
  STAGE(0, 0);

  int cur = 0;
  #pragma unroll 1
  for (int k = 0; k < NK; ++k) {
    VMCNT0;                              // own stage loads for tile k landed
    BAR;                                 // all waves staged k AND done reading buf[cur^1]
    if (k + 1 < NK) STAGE(cur ^ 1, (k + 1) << 6);

    const char* AsC = reinterpret_cast<const char*>(&As[cur][0]);
    const char* BsC = reinterpret_cast<const char*>(&Bs[cur][0]);
    #pragma unroll
    for (int kk = 0; kk < 2; ++kk) {
      short8 af[4], bfr[4];
      #pragma unroll
      for (int mi = 0; mi < 4; ++mi) {
        int row = wm*64 + mi*16 + (l & 15);
        int byte = row*128 + ((kk*64 + ((l >> 4) * 16)) ^ ((row & 7) << 4));
        af[mi] = *reinterpret_cast<const short8*>(AsC + byte);
      }
      #pragma unroll
      for (int ni = 0; ni < 4; ++ni) {
        int row = wn*64 + ni*16 + (l & 15);
        int byte = row*128 + ((kk*64 + ((l >> 4) * 16)) ^ ((row & 7) << 4));
        bfr[ni] = *reinterpret_cast<const short8*>(BsC + byte);
      }
      __builtin_amdgcn_s_setprio(1);
      #pragma unroll
      for (int mi = 0; mi < 4; ++mi)
        #pragma unroll
        for (int ni = 0; ni < 4; ++ni)
          acc[mi][ni] = __builtin_amdgcn_mfma_f32_16x16x32_bf16(af[mi], bfr[ni], acc[mi][ni], 0, 0, 0);
      __builtin_amdgcn_s_setprio(0);
    }
    cur ^= 1;
  }

  if (MODE == 0 && tn >= 2*EMB) {
    // ---- V block: transpose through LDS, emit VT[head][hd][n] ----
    ushort_t* T = &As[0][0];             // 1024 rowT x 16 els, 32KB
    #pragma unroll
    for (int mi = 0; mi < 4; ++mi) {
      #pragma unroll
      for (int ni = 0; ni < 4; ++ni) {
        #pragma unroll
        for (int r = 0; r < 4; ++r) {
          int rowl = wm*64 + mi*16 + ((l >> 4) * 4) + r;
          int coll = wn*64 + ni*16 + (l & 15);
          float v = acc[mi][ni][r] + bias[tn + coll];
          int b = rowl & 7, nloc = rowl >> 3;
          int hx = coll >> 6, hd = coll & 63;
          int rowT = (hx*8 + b)*64 + hd;
          int pc = (nloc >> 3) ^ (rowT & 1);
          T[rowT*16 + pc*8 + (nloc & 7)] = f2bf(v);
        }
      }
    }
    __syncthreads();
    const int hxg0 = (tn >> 6) & 7;
    #pragma unroll
    for (int i = 0; i < 8; ++i) {
      int c = i*256 + t;
      int rowT = c >> 1, lc = c & 1;
      int pc = lc ^ (rowT & 1);
      short8 val = *reinterpret_cast<const short8*>(&T[rowT*16 + pc*8]);
      int hx = rowT >> 9;
      int b  = (rowT >> 6) & 7;
      int hd = rowT & 63;
      int head = b*NHEAD + hxg0 + hx;
      size_t n = (size_t)(tm >> 3) + lc*8;
      *reinterpret_cast<short8*>(VTq + (size_t)head * HDIM * NSEQ + (size_t)hd * NSEQ + n) = val;
    }
    return;
  }

  #pragma unroll
  for (int mi = 0; mi < 4; ++mi) {
    #pragma unroll
    for (int ni = 0; ni < 4; ++ni) {
      #pragma unroll
      for (int r = 0; r < 4; ++r) {
        int row = tm + wm*64 + mi*16 + ((l >> 4) * 4) + r;
        int col = tn + wn*64 + ni*16 + (l & 15);
        float v = acc[mi][ni][r] + bias[col];
        if constexpr (MODE == 1) {
          Cf[(size_t)row * N + col] = v;
        } else {
          int w3 = col >> 9, hx = (col >> 6) & 7, hd = col & 63;
          int n = row >> 3, bb = row & 7;
          Cq[(size_t)w3 * ((size_t)NH_TOT * NSEQ * HDIM)
             + ((size_t)(bb * NHEAD + hx) * NSEQ + n) * HDIM + hd] = f2bf(v);
        }
      }
    }
  }
}

// ---------------- Flash attention (R12 structure, frozen at 84.6us) ----------------
#define CSC 0.18033688011112042f   /* (1/8) * log2(e) */

__global__ __launch_bounds__(256, 2) void attn_fwd(
    const ushort_t* __restrict__ Qb, const ushort_t* __restrict__ Kb,
    const ushort_t* __restrict__ VTb, ushort_t* __restrict__ Ob)
{
  __shared__ __align__(16) ushort_t Ks[2][2][64*64];
  __shared__ __align__(16) ushort_t Vs[2][2][64*64];
  const int t = threadIdx.x, w = t >> 6, l = t & 63;
  const int lq = l & 31, h = l >> 5;
  const int L = blockIdx.x + 8 * blockIdx.y;           // 0..511
  const int Tid = (L & 7) * 64 + (L >> 3);
  const int bh = Tid >> 3, qt = Tid & 7;
  const int b = bh >> 3, hh = bh & 7;
  const size_t hbase  = (size_t)bh * NSEQ * HDIM;
  const size_t vtbase = (size_t)bh * HDIM * NSEQ;
  const int qbase = qt*256 + w*64;

  short8 qreg[2][4];
  #pragma unroll
  for (int qb = 0; qb < 2; ++qb)
    #pragma unroll
    for (int kd = 0; kd < 4; ++kd) {
      short8 raw = *reinterpret_cast<const short8*>(
          Qb + hbase + (size_t)(qbase + qb*32 + lq) * HDIM + kd*16 + h*8);
      short8 q;
      #pragma unroll
      for (int e = 0; e < 8; ++e)
        q[e] = (short)f2bf(bf2f((ushort_t)raw[e]) * CSC);
      qreg[qb][kd] = q;
    }

  f32x16 Oacc[2][2] = {};     // [qb][dt]
  f32x16 lacc0 = {}, lacc1 = {};

  const short ONE = (short)0x3F80;  // bf16 1.0
  short8 ones = { ONE, ONE, ONE, ONE, ONE, ONE, ONE, ONE };

  const int srow = t >> 3;
  const int scol = (t & 7) * 8;
  const int c0 = scol ^ (SW(srow) << 3);
  const int c1 = scol ^ (SW(srow + 32) << 3);
  const ushort_t* Kg0 = Kb  + hbase  + (size_t)srow       * HDIM + c0;
  const ushort_t* Kg1 = Kb  + hbase  + (size_t)(srow+32)  * HDIM + c1;
  const ushort_t* Vg0 = VTb + vtbase + (size_t)srow       * NSEQ + c0;
  const ushort_t* Vg1 = VTb + vtbase + (size_t)(srow+32)  * NSEQ + c1;

  auto STAGE = [&](int bi, int p) {
    #pragma unroll
    for (int ss = 0; ss < 2; ++ss) {
      int kt = p*2 + ss;
      size_t ko = (size_t)kt * 64 * HDIM;
      int    vo = kt * 64;
      gll16(Kg0 + ko, &Ks[bi][ss][0]    + t*8);
      gll16(Kg1 + ko, &Ks[bi][ss][2048] + t*8);
      gll16(Vg0 + vo, &Vs[bi][ss][0]    + t*8);
      gll16(Vg1 + vo, &Vs[bi][ss][2048] + t*8);
    }
  };

  VMCNT0;
  STAGE(0, 0);

  int cur = 0;
  #pragma unroll 1
  for (int p = 0; p < NP; ++p) {
    VMCNT0;
    BAR;
    if (p + 1 < NP) STAGE(cur ^ 1, p + 1);

    #pragma unroll
    for (int ss = 0; ss < 2; ++ss) {
      const char* KsC = reinterpret_cast<const char*>(&Ks[cur][ss][0]);
      const char* VsC = reinterpret_cast<const char*>(&Vs[cur][ss][0]);

      short8 kf[2][4];
      #pragma unroll
      for (int rp = 0; rp < 2; ++rp) {
        int row = rp*32 + lq;
        int swr = SW(row) << 4;
        #pragma unroll
        for (int kd = 0; kd < 4; ++kd)
          kf[rp][kd] = *reinterpret_cast<const short8*>(
              KsC + row*128 + ((kd*32 + h*16) ^ swr));
      }

      uint32 pa0[4][4], pa1[4][4];

      // ===== q-block 0: QK -> exp -> pack =====
      {
        f32x16 s0 = {}, s1 = {};
        __builtin_amdgcn_s_setprio(1);
        #pragma unroll
        for (int kd = 0; kd < 4; ++kd) {
          s0 = __builtin_amdgcn_mfma_f32_32x32x16_bf16(kf[0][kd], qreg[0][kd], s0, 0, 0, 0);
          s1 = __builtin_amdgcn_mfma_f32_32x32x16_bf16(kf[1][kd], qreg[0][kd], s1, 0, 0, 0);
        }
        __builtin_amdgcn_s_setprio(0);
        #pragma unroll
        for (int r = 0; r < 16; ++r) {
          s0[r] = __builtin_amdgcn_exp2f(s0[r]);
          s1[r] = __builtin_amdgcn_exp2f(s1[r]);
        }
        uint32 w0[8], w1[8];
        #pragma unroll
        for (int i = 0; i < 8; ++i) {
          float a0 = s0[2*i], b0 = s0[2*i+1];
          float a1 = s1[2*i], b1 = s1[2*i+1];
          asm("v_cvt_pk_bf16_f32 %0, %1, %2" : "=v"(w0[i]) : "v"(a0), "v"(b0));
          asm("v_cvt_pk_bf16_f32 %0, %1, %2" : "=v"(w1[i]) : "v"(a1), "v"(b1));
        }
        #pragma unroll
        for (int sg = 0; sg < 2; ++sg) {
          uint32 a, bb;
          a = w0[4*sg+0]; bb = w0[4*sg+2];
          asm("v_permlane32_swap_b32 %0, %1" : "+v"(a), "+v"(bb));
          pa0[sg][0] = a; pa0[sg][2] = bb;
          a = w0[4*sg+1]; bb = w0[4*sg+3];
          asm("v_permlane32_swap_b32 %0, %1" : "+v"(a), "+v"(bb));
          pa0[sg][1] = a; pa0[sg][3] = bb;
          a = w1[4*sg+0]; bb = w1[4*sg+2];
          asm("v_permlane32_swap_b32 %0, %1" : "+v"(a), "+v"(bb));
          pa0[2+sg][0] = a; pa0[2+sg][2] = bb;
          a = w1[4*sg+1]; bb = w1[4*sg+3];
          asm("v_permlane32_swap_b32 %0, %1" : "+v"(a), "+v"(bb));
          pa0[2+sg][1] = a; pa0[2+sg][3] = bb;
        }
      }

      // ===== q-block 1 =====
      {
        f32x16 s0 = {}, s1 = {};
        __builtin_amdgcn_s_setprio(1);
        #pragma unroll
        for (int kd = 0; kd < 4; ++kd) {
          s0 = __builtin_amdgcn_mfma_f32_32x32x16_bf16(kf[0][kd], qreg[1][kd], s0, 0, 0, 0);
          s1 = __builtin_amdgcn_mfma_f32_32x32x16_bf16(kf[1][kd], qreg[1][kd], s1, 0, 0, 0);
        }
        __builtin_amdgcn_s_setprio(0);
        #pragma unroll
        for (int r = 0; r < 16; ++r) {
          s0[r] = __builtin_amdgcn_exp2f(s0[r]);
          s1[r] = __builtin_amdgcn_exp2f(s1[r]);
        }
        uint32 w0[8], w1[8];
        #pragma unroll
        for (int i = 0; i < 8; ++i) {
          float a0 = s0[2*i], b0 = s0[2*i+1];
          float a1 = s1[2*i], b1 = s1[2*i+1];
          asm("v_cvt_pk_bf16_f32 %0, %1, %2" : "=v"(w0[i]) : "v"(a0), "v"(b0));
          asm("v_cvt_pk_bf16_f32 %0, %1, %2" : "=v"(w1[i]) : "v"(a1), "v"(b1));
        }
        #pragma unroll
        for (int sg = 0; sg < 2; ++sg) {
          uint32 a, bb;
          a = w0[4*sg+0]; bb = w0[4*sg+2];
          asm("v_permlane32_swap_b32 %0, %1" : "+v"(a), "+v"(bb));
          pa1[sg][0] = a; pa1[sg][2] = bb;
          a = w0[4*sg+1]; bb = w0[4*sg+3];
          asm("v_permlane32_swap_b32 %0, %1" : "+v"(a), "+v"(bb));
          pa1[sg][1] = a; pa1[sg][3] = bb;
          a = w1[4*sg+0]; bb = w1[4*sg+2];
          asm("v_permlane32_swap_b32 %0, %1" : "+v"(a), "+v"(bb));
          pa1[2+sg][0] = a; pa1[2+sg][2] = bb;
          a = w1[4*sg+1]; bb = w1[4*sg+3];
          asm("v_permlane32_swap_b32 %0, %1" : "+v"(a), "+v"(bb));
          pa1[2+sg][1] = a; pa1[2+sg][3] = bb;
        }
      }

      short8 vf[2][4];
      #pragma unroll
      for (int dt = 0; dt < 2; ++dt) {
        int d = dt*32 + lq;
        int swd = SW(d) << 4;
        #pragma unroll
        for (int km = 0; km < 4; ++km)
          vf[dt][km] = *reinterpret_cast<const short8*>(
              VsC + d*128 + ((km*32 + h*16) ^ swd));
      }

      __builtin_amdgcn_s_setprio(1);
      #pragma unroll
      for (int km = 0; km < 4; ++km) {
        uint4v u0; u0[0] = pa0[km][0]; u0[1] = pa0[km][1]; u0[2] = pa0[km][2]; u0[3] = pa0[km][3];
        short8 paf0 = __builtin_bit_cast(short8, u0);
        uint4v u1; u1[0] = pa1[km][0]; u1[1] = pa1[km][1]; u1[2] = pa1[km][2]; u1[3] = pa1[km][3];
        short8 paf1 = __builtin_bit_cast(short8, u1);
        Oacc[0][0] = __builtin_amdgcn_mfma_f32_32x32x16_bf16(paf0, vf[0][km], Oacc[0][0], 0, 0, 0);
        lacc0      = __builtin_amdgcn_mfma_f32_32x32x16_bf16(paf0, ones,     lacc0,      0, 0, 0);
        Oacc[0][1] = __builtin_amdgcn_mfma_f32_32x32x16_bf16(paf0, vf[1][km], Oacc[0][1], 0, 0, 0);
        Oacc[1][0] = __builtin_amdgcn_mfma_f32_32x32x16_bf16(paf1, vf[0][km], Oacc[1][0], 0, 0, 0);
        lacc1      = __builtin_amdgcn_mfma_f32_32x32x16_bf16(paf1, ones,     lacc1,      0, 0, 0);
        Oacc[1][1] = __builtin_amdgcn_mfma_f32_32x32x16_bf16(paf1, vf[1][km], Oacc[1][1], 0, 0, 0);
      }
      __builtin_amdgcn_s_setprio(0);
    }

    cur ^= 1;
  }

  #pragma unroll
  for (int r = 0; r < 16; ++r) {
    int qrow = (r & 3) + 8*(r >> 2) + 4*h;
    float li0 = __builtin_amdgcn_rcpf(lacc0[r]);
    float li1 = __builtin_amdgcn_rcpf(lacc1[r]);
    #pragma unroll
    for (int dt = 0; dt < 2; ++dt) {
      int d = dt*32 + lq;
      int n0 = qbase + qrow;
      int n1 = qbase + 32 + qrow;
      Ob[((size_t)n0 * BSZ + b) * EMB + hh*64 + d] = f2bf(Oacc[0][dt][r] * li0);
      Ob[((size_t)n1 * BSZ + b) * EMB + hh*64 + d] = f2bf(Oacc[1][dt][r] * li1);
    }
  }
}

extern "C" void kernel_launch(void* const* d_in, const int* in_sizes, int n_in,
                              void* d_out, int out_size, void* d_ws, size_t ws_size,
                              hipStream_t stream) {
  (void)in_sizes; (void)n_in; (void)out_size; (void)ws_size;
  const float* seq  = (const float*)d_in[0];
  const float* Wqkv = (const float*)d_in[1];
  const float* bqkv = (const float*)d_in[2];
  const float* Wout = (const float*)d_in[3];
  const float* bout = (const float*)d_in[4];
  float* out = (float*)d_out;

  ushort_t* seq_bf  = (ushort_t*)d_ws;
  ushort_t* wqkv_bf = seq_bf  + (size_t)MTOK * EMB;
  ushort_t* wout_bf = wqkv_bf + (size_t)3 * EMB * EMB;
  ushort_t* qkvbuf  = wout_bf + (size_t)EMB * EMB;
  ushort_t* vtbuf   = qkvbuf  + (size_t)3 * NH_TOT * NSEQ * HDIM;
  // attn output aliases the (unwritten) V region of qkvbuf
  ushort_t* attno   = qkvbuf  + (size_t)2 * NH_TOT * NSEQ * HDIM;

  const int na8 = MTOK*EMB/8, nb8 = 3*EMB*EMB/8, nc8 = EMB*EMB/8;
  cvt3<<<2048, 256, 0, stream>>>(
      seq, seq_bf, na8, Wqkv, wqkv_bf, nb8, Wout, wout_bf, nc8);

  gemm_bt<0><<<dim3(12, 128), 256, 0, stream>>>(seq_bf, wqkv_bf, bqkv, nullptr, qkvbuf,
                                                vtbuf, MTOK, 3*EMB, EMB);

  const ushort_t* Qb  = qkvbuf;
  const ushort_t* Kb  = qkvbuf + (size_t)NH_TOT * NSEQ * HDIM;

  attn_fwd<<<dim3(8, 64), 256, 0, stream>>>(Qb, Kb, vtbuf, attno);

  gemm_bt<1><<<dim3(4, 128), 256, 0, stream>>>(attno, wout_bf, bout, out, nullptr,
                                               nullptr, MTOK, EMB, EMB);
}